// Round 13
// baseline (345.836 us; speedup 1.0000x reference)
//
#include <hip/hip_runtime.h>
#include <hip/hip_bf16.h>

typedef __hip_bfloat16 bf16;
typedef __attribute__((ext_vector_type(8))) short short8;
typedef __attribute__((ext_vector_type(4))) float floatx4;

#define BBB 8
#define LL 2048
#define DDD 512
#define II 256
#define SS 8
#define MM (BBB*LL)      // 16384 rows
#define CHUNK 64
#define NCH (LL/CHUNK)   // 32

// ---- workspace (bytes); proven ws_size >= 131,072,000 ----
#define WS_SI    0l          // si bf16 [M,512]            -> 16,777,216
#define WS_U0    16777216l   // u0 bf16 [M,512] (y0|zb0)   -> 33,554,432
#define WS_U1    33554432l   // u1 bf16 [M,512] (y1|zb1)   -> 50,331,648
#define WS_XZ    50331648l   // xz bf16 [M,1024]           -> 83,886,080
//   XZ region reuse (disjoint lifetimes):
#define WS_H     67108864l   // H bf16 [M,128] (early)           -> +4,194,304
#define WS_P     50331648l   // P f32 [16][32][2048] (after conv)-> +4,194,304
#define WS_Q     58720256l   // Q f32                            -> +4,194,304
#define WS_SINB  67108864l   // sinb f32                         -> +4,194,304
#define WS_XBC   83886080l   // xbc bf16 [2][M,256]        -> 100,663,296
#define WS_MIXED 83886080l   // mixed bf16 [M,512] (alias xbc, after scan)
#define WS_DELTA 100663296l  // delta bf16 [2][M,256]      -> 117,440,512
//   DELTA region reuse: xb16 bf16 [M,512] (early: prep -> posout GEMM)
#define WS_BTCT  117440512l  // btct f32 [2][M,16]         -> 121,634,816
#define WS_INWB  121634816l  // in_w  bf16 [1024,512]      -> 122,683,392
#define WS_MIXWB 122683392l  // mix_w bf16 [512,1536]      -> 124,256,256
#define WS_PW2B  124256256l  // pos_w2 bf16 [512,128]      -> 124,387,328
#define WS_OWT   124387328l  // out_w^T bf16 [2][512,512]  -> 125,435,904
#define WS_WP    125435904l  // W' bf16 [2][512,512]       -> 126,484,480
#define WS_WD    126484480l  // Wd bf16 [2][256][256]      -> 126,746,624
#define WS_XPWB  126746624l  // xp_w[32:48] bf16 [2][16][256] -> 126,763,008
#define WS_A2    126763008l  // a2 f32 [2][256][8]         -> 126,779,392
#define WS_WXT   126779392l  // wxT f32 [2][3][256] (k pre-flipped for d=1) -> 126,785,536
#define WS_WZT   126785536l  // wzT f32 [2][3][256] (k pre-flipped for d=1) -> 126,791,680
#define WS_MRS   126791680l  // mrs f32 [M][2] (mean,rstd of x rows) -> 126,922,752
#define WS_LNBP  126922752l  // lnbp f32 [512] = ln_in_b + pos_b2    -> 126,924,800

// ---------------- helpers ----------------
__device__ __forceinline__ float b2f(unsigned short u) {
    return __uint_as_float(((unsigned)u) << 16);
}
__device__ __forceinline__ float bload(const bf16* p) {
    return b2f(*(const unsigned short*)p);
}
__device__ __forceinline__ void bstore(bf16* p, float v) {
    *p = __float2bfloat16(v);
}
__device__ __forceinline__ float softplus_f(float x) {
    return fmaxf(x, 0.f) + log1pf(expf(-fabsf(x)));
}
__device__ __forceinline__ float silu_f(float x) {
    return x / (1.f + expf(-x));
}
// async global->LDS, 16 bytes per lane; LDS dest is wave-uniform base + lane*16
__device__ __forceinline__ void gl_lds16(const bf16* g, void* l) {
    __builtin_amdgcn_global_load_lds(
        (const __attribute__((address_space(1))) unsigned int*)g,
        (__attribute__((address_space(3))) unsigned int*)l, 16, 0, 0);
}
// counted-vmcnt pipeline primitives (T4): barrier-after-own-vmcnt = collective wait
#define VMWAIT_N(n) asm volatile("s_waitcnt vmcnt(" #n ")" ::: "memory")
#define VMWAIT0() asm volatile("s_waitcnt vmcnt(0)" ::: "memory")
#define XBAR()    __builtin_amdgcn_s_barrier()

// wave-level (64-lane) mean/rstd: xor butterfly, all lanes get result, no barriers
__device__ __forceinline__ void wave_mean_rstd(float s, float q,
                                               float& mean, float& rstd) {
    #pragma unroll
    for (int off = 1; off < 64; off <<= 1) {
        s += __shfl_xor(s, off);
        q += __shfl_xor(q, off);
    }
    mean = s * (1.f/DDD);
    float var = q * (1.f/DDD) - mean*mean;
    rstd = rsqrtf(var + 1e-6f);
}

// ---------------- merged prep kernel ----------------
// sections by blockIdx.x:
// [0,4096) x row stats (wave-per-row, 4 rows/block) + x->bf16
// [4096,12288) k_h | [12288,14336) tow | [14336,15104) f2b mix
// [15104,15616) f2b in_w | [15616,16128) wd | [16128,16192) f2b pos_w2
// [16192,16224) xpw16 | [16224,16240) aprep | [16240,16246) wt | [16246,16248) lnbp
__global__ __launch_bounds__(256)
void k_prep(const float* __restrict__ x, float* __restrict__ mrs,
            bf16* __restrict__ xb16,
            const float* __restrict__ lnb, const float* __restrict__ pb2,
            float* __restrict__ lnbp,
            const float* __restrict__ position, const float* __restrict__ pw1,
            const float* __restrict__ pb1, bf16* __restrict__ H,
            const float* __restrict__ ow, bf16* __restrict__ owT,
            const float* __restrict__ mixw, bf16* __restrict__ mixwb,
            const float* __restrict__ inw, bf16* __restrict__ inwb,
            const float* __restrict__ dtw, const float* __restrict__ xpw,
            bf16* __restrict__ Wd,
            const float* __restrict__ posw2, bf16* __restrict__ pw2b,
            bf16* __restrict__ xpwb,
            const float* __restrict__ Alog, float* __restrict__ a2,
            const float* __restrict__ cxw, const float* __restrict__ czw,
            float* __restrict__ wxT, float* __restrict__ wzT) {
    int bb = blockIdx.x;
    int tid = threadIdx.x;
    if (bb < 4096) {                     // x row stats + bf16 copy (wave-per-row)
        long row = (long)bb*4 + (tid >> 6);
        int lane = tid & 63;
        const float* xr = x + row*DDD;
        float4 a = *(const float4*)(xr + lane*4);
        float4 c = *(const float4*)(xr + 256 + lane*4);
        bf16 t0[4] = {__float2bfloat16(a.x), __float2bfloat16(a.y),
                      __float2bfloat16(a.z), __float2bfloat16(a.w)};
        bf16 t1[4] = {__float2bfloat16(c.x), __float2bfloat16(c.y),
                      __float2bfloat16(c.z), __float2bfloat16(c.w)};
        *(ushort4*)(xb16 + row*DDD + lane*4)       = *(ushort4*)t0;
        *(ushort4*)(xb16 + row*DDD + 256 + lane*4) = *(ushort4*)t1;
        float s = a.x+a.y+a.z+a.w + c.x+c.y+c.z+c.w;
        float q = a.x*a.x+a.y*a.y+a.z*a.z+a.w*a.w
                + c.x*c.x+c.y*c.y+c.z*c.z+c.w*c.w;
        float mean, rstd;
        wave_mean_rstd(s, q, mean, rstd);
        if (lane == 0) { mrs[row*2] = mean; mrs[row*2+1] = rstd; }
    } else if (bb < 12288) {             // H = gelu(position @ pw1^T + pb1)
        long idx = (long)(bb - 4096)*256 + tid;
        long row = idx >> 7; int ph = idx & 127;
        const float* p = position + row*6;
        const float* w = pw1 + ph*6;
        float v = pb1[ph];
        #pragma unroll
        for (int j = 0; j < 6; ++j) v = fmaf(p[j], w[j], v);
        v = 0.5f * v * (1.f + erff(v * 0.70710678118654752440f));
        bstore(H + idx, v);
    } else if (bb < 14336) {             // owT[d][k][c] = out_w[d][c][k]
        long idx = (long)(bb - 12288)*256 + tid;
        long d = idx >> 18; long rem = idx & 262143;
        long k = rem >> 9, c = rem & 511;
        bstore(owT + idx, ow[d*262144 + c*512 + k]);
    } else if (bb < 15104) {             // f2b mix_w (786432)
        int i = (bb - 14336)*256*4 + tid*4;
        float4 v = *(const float4*)(mixw + i);
        bf16 t[4] = {__float2bfloat16(v.x), __float2bfloat16(v.y),
                     __float2bfloat16(v.z), __float2bfloat16(v.w)};
        *(ushort4*)(mixwb + i) = *(ushort4*)t;
    } else if (bb < 15616) {             // f2b in_w (524288)
        int i = (bb - 15104)*256*4 + tid*4;
        float4 v = *(const float4*)(inw + i);
        bf16 t[4] = {__float2bfloat16(v.x), __float2bfloat16(v.y),
                     __float2bfloat16(v.z), __float2bfloat16(v.w)};
        *(ushort4*)(inwb + i) = *(ushort4*)t;
    } else if (bb < 16128) {             // Wd[d] = dt_w[d] @ xp_w[d][:32,:]
        int local = bb - 15616;
        int d = local >> 8, i = local & 255, j = tid;
        const float* wr = dtw + (long)d*II*32 + i*32;
        const float* xp = xpw + (long)d*48*II;
        float acc = 0.f;
        #pragma unroll
        for (int k = 0; k < 32; ++k) acc = fmaf(wr[k], xp[k*II + j], acc);
        bstore(Wd + ((long)d*II + i)*II + j, acc);
    } else if (bb < 16192) {             // f2b pos_w2 (65536)
        int i = (bb - 16128)*256*4 + tid*4;
        float4 v = *(const float4*)(posw2 + i);
        bf16 t[4] = {__float2bfloat16(v.x), __float2bfloat16(v.y),
                     __float2bfloat16(v.z), __float2bfloat16(v.w)};
        *(ushort4*)(pw2b + i) = *(ushort4*)t;
    } else if (bb < 16224) {             // xpwb (8192)
        int idx = (bb - 16192)*256 + tid;
        int d = idx >> 12, rem = idx & 4095;
        bstore(xpwb + idx, xpw[(long)d*48*II + 32*II + rem]);
    } else if (bb < 16240) {             // a2 (4096)
        int idx = (bb - 16224)*256 + tid;
        float a = softplus_f(Alog[idx]) + 1e-4f;
        a2[idx] = -1.4426950408889634f * a;
    } else if (bb < 16246) {             // conv weight transpose (1536)
        int idx = (bb - 16240)*256 + tid;
        if (idx < 1536) {
            int d = idx / 768, rem = idx % 768;
            int k = rem >> 8, i = rem & 255;
            int kk = d ? (2 - k) : k;
            wxT[idx] = cxw[d*768 + i*3 + kk];
            wzT[idx] = czw[d*768 + i*3 + kk];
        }
    } else {                             // lnbp (512)
        int idx = (bb - 16246)*256 + tid;
        lnbp[idx] = lnb[idx] + pb2[idx];
    }
}

// ---- shared GEMM body macro; expects KKN, MASKC, wm/wn/lr/lq, acc in scope ----
#define GEMM_COMPUTE(Sa, Sb)                                                      \
    do {                                                                          \
        _Pragma("unroll")                                                         \
        for (int kk = 0; kk < KKN; ++kk) {                                        \
            const int sa_ = ((kk*4 + lq) ^ (lr & MASKC)) * 16;                    \
            short8 af[4], bfr[4];                                                 \
            _Pragma("unroll")                                                     \
            for (int mi = 0; mi < 4; ++mi)                                        \
                af[mi] = *(const short8*)((const char*)&Sa[wm*64 + mi*16 + lr][0] + sa_); \
            _Pragma("unroll")                                                     \
            for (int ni = 0; ni < 4; ++ni)                                        \
                bfr[ni] = *(const short8*)((const char*)&Sb[wn*64 + ni*16 + lr][0] + sa_); \
            _Pragma("unroll")                                                     \
            for (int mi = 0; mi < 4; ++mi)                                        \
                _Pragma("unroll")                                                 \
                for (int ni = 0; ni < 4; ++ni)                                    \
                    acc[mi][ni] = __builtin_amdgcn_mfma_f32_16x16x32_bf16(        \
                        af[mi], bfr[ni], acc[mi][ni], 0, 0, 0);                   \
        }                                                                         \
    } while (0)

// ---------------- pipelined MFMA GEMM: C[M,N] = A[M,K] @ B^T ----------------
// BK=64. Depth-2 prefetch, counted vmcnt(8) + raw s_barrier (T4), static
// buffer names, XOR-swizzled LDS via pre-swizzled global source, XCD swizzle.
// Kdim must be a multiple of 128 (NT even) -- true at all call sites.
// EPI 0: plain store; EPI 1: clip(softplus(v+bias[col]));
// EPI 2: v += (xb16[row,col]-mean[row])*rstd[row]*lnw[col] + lnbp[col]
template<typename TC, int EPI = 0>
__global__ __launch_bounds__(256)
void gemm_mfma(const bf16* __restrict__ A, long lda,
               const bf16* __restrict__ B, long ldb,
               TC* __restrict__ C, long ldc, int Kdim,
               const float* __restrict__ bias,
               long zA, long zB, long zC, long zbias,
               const bf16* __restrict__ xb16, const float* __restrict__ mrs,
               const float* __restrict__ lnw, const float* __restrict__ lnbp) {
    enum { KKN = 2, MASKC = 7 };
    __shared__ short As0[128][64], Bs0[128][64];
    __shared__ short As1[128][64], Bs1[128][64];
    const int tid = threadIdx.x;
    const int lane = tid & 63;
    const int wave = tid >> 6;
    const int wm = wave >> 1, wn = wave & 1;
    const int lr = lane & 15, lq = lane >> 4;
    A += (long)blockIdx.z * zA;
    B += (long)blockIdx.z * zB;
    C += (long)blockIdx.z * zC;
    const float* bp = bias ? bias + (long)blockIdx.z * zbias : nullptr;
    // XCD-aware swizzle (all call sites have nwg % 8 == 0)
    int nwg = gridDim.x * gridDim.y;
    int bid = blockIdx.y * gridDim.x + blockIdx.x;
    int wg = (bid & 7) * (nwg >> 3) + (bid >> 3);
    const long m0 = (long)(wg / gridDim.x) * 128;
    const long n0 = (long)(wg % gridDim.x) * 128;

    // staging descriptors: LDS chunk ch = r*8+c holds global chunk (r, c^(r&7))
    const bf16* gA[4]; const bf16* gB[4]; int off16[4];
    #pragma unroll
    for (int q = 0; q < 4; ++q) {
        int ch = q*256 + tid;
        int r = ch >> 3;
        int g = (ch & 7) ^ (r & 7);
        gA[q] = A + (m0 + r)*lda + g*8;
        gB[q] = B + (n0 + r)*ldb + g*8;
        off16[q] = (q*256 + wave*64) * 16;   // wave-uniform LDS byte base
    }
#define STAGE_G(Sa, Sb, k0)                                   \
    do {                                                      \
        _Pragma("unroll")                                     \
        for (int q = 0; q < 4; ++q) {                         \
            gl_lds16(gA[q] + (k0), (char*)(Sa) + off16[q]);   \
            gl_lds16(gB[q] + (k0), (char*)(Sb) + off16[q]);   \
        }                                                     \
    } while (0)

    floatx4 acc[4][4];
    #pragma unroll
    for (int i = 0; i < 4; ++i)
        #pragma unroll
        for (int j = 0; j < 4; ++j)
            acc[i][j] = (floatx4){0.f, 0.f, 0.f, 0.f};

    const int NT = Kdim >> 6;
    STAGE_G(As0, Bs0, 0);
    STAGE_G(As1, Bs1, 64);
    int t = 0;
    for (; t + 2 < NT; t += 2) {
        VMWAIT_N(8); XBAR();                     // S0 tile ready (collective)
        GEMM_COMPUTE(As0, Bs0);
        XBAR();                                  // all reads of S0 done
        STAGE_G(As0, Bs0, (long)(t + 2) << 6);
        VMWAIT_N(8); XBAR();                     // S1 tile ready
        GEMM_COMPUTE(As1, Bs1);
        XBAR();
        STAGE_G(As1, Bs1, (long)(t + 3) << 6);
    }
    VMWAIT_N(8); XBAR();
    GEMM_COMPUTE(As0, Bs0);
    VMWAIT0(); XBAR();
    GEMM_COMPUTE(As1, Bs1);
#undef STAGE_G
    #pragma unroll
    for (int mi = 0; mi < 4; ++mi)
        #pragma unroll
        for (int ni = 0; ni < 4; ++ni)
            #pragma unroll
            for (int r = 0; r < 4; ++r) {
                long row = m0 + wm*64 + mi*16 + lq*4 + r;
                long col = n0 + wn*64 + ni*16 + lr;
                float v = acc[mi][ni][r];
                if (EPI == 1)
                    v = fminf(fmaxf(softplus_f(v + bp[col]), 1e-4f), 1.0f);
                if (EPI == 2) {
                    float2 ms = *(const float2*)(mrs + row*2);
                    v += (bload(xb16 + row*512 + col) - ms.x)*ms.y*lnw[col] + lnbp[col];
                }
                if constexpr (sizeof(TC) == 2) bstore((bf16*)C + row*ldc + col, v);
                else ((float*)C)[row*ldc + col] = v;
            }
}

// ---------------- btct: tanh(xbc @ xpwb^T) -> f32 [2][M,16]; per-wave 16x16 tile ----------------
__global__ __launch_bounds__(256) void k_btct(const bf16* __restrict__ xbc,
                                              const bf16* __restrict__ xpwb,
                                              float* __restrict__ btct) {
    int d = blockIdx.y;
    int wave = threadIdx.x >> 6, lane = threadIdx.x & 63;
    long r0 = (long)blockIdx.x*64 + wave*16;
    int lr = lane & 15, lq = lane >> 4;
    const bf16* xb = xbc  + (long)d*MM*II;
    const bf16* wp = xpwb + (long)d*16*II;
    floatx4 acc = (floatx4){0.f, 0.f, 0.f, 0.f};
    #pragma unroll
    for (int k0 = 0; k0 < II; k0 += 32) {
        short8 af = *(const short8*)(xb + (r0 + lr)*II + k0 + lq*8);
        short8 bf = *(const short8*)(wp + lr*II + k0 + lq*8);
        acc = __builtin_amdgcn_mfma_f32_16x16x32_bf16(af, bf, acc, 0, 0, 0);
    }
    #pragma unroll
    for (int r = 0; r < 4; ++r) {
        long row = r0 + lq*4 + r;
        btct[((long)d*MM + row)*16 + lr] = tanhf(acc[r]);
    }
}

// ---------------- depthwise conv3 + SiLU (8 ch x 4 rows per thread) ----------------
// grid (512, 2): idx over MM/4 row-groups x 32 channel-groups
__global__ __launch_bounds__(256) void k_conv(const bf16* __restrict__ xz,
                                              const float* __restrict__ wxT,
                                              const float* __restrict__ wzT,
                                              bf16* __restrict__ xbc,
                                              bf16* __restrict__ u0,
                                              bf16* __restrict__ u1) {
    int d = blockIdx.y;
    long idx = (long)blockIdx.x*256 + threadIdx.x;   // over (MM/4)*32 = 131072
    long rg = idx >> 5; int i = (int)(idx & 31) * 8;
    long row0 = rg << 2;
    int l0 = (int)(row0 & (LL-1));                    // multiple of 4
    // weights for this thread's 8 channels: 12 coalesced float4 loads, k pre-flipped
    const float* wxp = wxT + d*768 + i;
    const float* wzp = wzT + d*768 + i;
    float wxr[3][8], wzr[3][8];
    #pragma unroll
    for (int k = 0; k < 3; ++k) {
        *(float4*)&wxr[k][0] = *(const float4*)(wxp + k*256);
        *(float4*)&wxr[k][4] = *(const float4*)(wxp + k*256 + 4);
        *(float4*)&wzr[k][0] = *(const float4*)(wzp + k*256);
        *(float4*)&wzr[k][4] = *(const float4*)(wzp + k*256 + 4);
    }
    const bf16* base = xz + row0*1024 + (long)d*512 + i;
    short8 X[6], Z[6];
    #pragma unroll
    for (int k = 0; k < 6; ++k) {
        int gl = l0 - 1 + k;
        bool ok = (gl >= 0) && (gl < LL);
        if (ok) {
            X[k] = *(const short8*)(base + (long)(k-1)*1024);
            Z[k] = *(const short8*)(base + (long)(k-1)*1024 + 256);
        } else {
            X[k] = (short8){0,0,0,0,0,0,0,0};
            Z[k] = (short8){0,0,0,0,0,0,0,0};
        }
    }
    bf16* u = d ? u1 : u0;
    #pragma unroll
    for (int r = 0; r < 4; ++r) {
        bf16 ox[8], oz[8];
        #pragma unroll
        for (int j = 0; j < 8; ++j) {
            float ax = 0.f, az = 0.f;
            #pragma unroll
            for (int k = 0; k < 3; ++k) {
                ax = fmaf(b2f((unsigned short)X[r+k][j]), wxr[k][j], ax);
                az = fmaf(b2f((unsigned short)Z[r+k][j]), wzr[k][j], az);
            }
            ox[j] = __float2bfloat16(silu_f(ax));
            oz[j] = __float2bfloat16(silu_f(az));
        }
        *(short8*)(xbc + (long)d*MM*II + (row0+r)*II + i) = *(short8*)ox;
        *(short8*)(u + (row0+r)*512 + 256 + i) = *(short8*)oz;
    }
}

// ---------------- pipelined segmented GEMM: mixed = [A0|A1|A2] @ [B0|B1|B2]^T -> bf16 ----------------
__global__ __launch_bounds__(256)
void gemm_mix3(const bf16* __restrict__ A0, const bf16* __restrict__ A1,
               const bf16* __restrict__ A2,
               const bf16* __restrict__ B0, const bf16* __restrict__ B1,
               const bf16* __restrict__ B2, long ldb2,
               bf16* __restrict__ C) {
    enum { KKN = 2, MASKC = 7 };
    __shared__ short As0[128][64], Bs0[128][64];
    __shared__ short As1[128][64], Bs1[128][64];
    const int tid = threadIdx.x;
    const int lane = tid & 63;
    const int wave = tid >> 6;
    const int wm = wave >> 1, wn = wave & 1;
    const int lr = lane & 15, lq = lane >> 4;
    int nwg = gridDim.x * gridDim.y;
    int bid = blockIdx.y * gridDim.x + blockIdx.x;
    int wg = (bid & 7) * (nwg >> 3) + (bid >> 3);
    const long m0 = (long)(wg / gridDim.x) * 128;
    const long n0 = (long)(wg % gridDim.x) * 128;

    long aoff[4], boffA[4], boffB[4]; int off16[4];
    #pragma unroll
    for (int q = 0; q < 4; ++q) {
        int ch = q*256 + tid;
        int r = ch >> 3;
        int g = (ch & 7) ^ (r & 7);
        aoff[q]  = (m0 + r)*512 + g*8;
        boffA[q] = (n0 + r)*512 + g*8;
        boffB[q] = (n0 + r)*ldb2 + g*8;
        off16[q] = (q*256 + wave*64) * 16;
    }
#define STAGE_M(Sa, Sb, t)                                                   \
    do {                                                                     \
        int seg_ = (t) >> 3;                                                 \
        long kc_ = ((long)(t) << 6) & 511;                                   \
        const bf16* Ap_ = (seg_ == 0) ? A0 : (seg_ == 1 ? A1 : A2);          \
        const bf16* Bp_ = (seg_ == 0) ? B0 : (seg_ == 1 ? B1 : B2);          \
        _Pragma("unroll")                                                    \
        for (int q = 0; q < 4; ++q) {                                        \
            gl_lds16(Ap_ + aoff[q] + kc_, (char*)(Sa) + off16[q]);           \
            gl_lds16(Bp_ + (seg_ < 2 ? boffA[q] : boffB[q]) + kc_,           \
                     (char*)(Sb) + off16[q]);                                \
        }                                                                    \
    } while (0)

    floatx4 acc[4][4];
    #pragma unroll
    for (int i = 0; i < 4; ++i)
        #pragma unroll
        for (int j = 0; j < 4; ++j)
            acc[i][j] = (floatx4){0.f, 0.f, 0.f, 0.f};

    STAGE_M(As0, Bs0, 0);
    STAGE_M(As1, Bs1, 1);
    int t = 0;
    for (; t + 2 < 24; t += 2) {
        VMWAIT_N(8); XBAR();
        GEMM_COMPUTE(As0, Bs0);
        XBAR();
        STAGE_M(As0, Bs0, t + 2);
        VMWAIT_N(8); XBAR();
        GEMM_COMPUTE(As1, Bs1);
        XBAR();
        STAGE_M(As1, Bs1, t + 3);
    }
    VMWAIT_N(8); XBAR();
    GEMM_COMPUTE(As0, Bs0);
    VMWAIT0(); XBAR();
    GEMM_COMPUTE(As1, Bs1);
#undef STAGE_M
    #pragma unroll
    for (int mi = 0; mi < 4; ++mi)
        #pragma unroll
        for (int ni = 0; ni < 4; ++ni)
            #pragma unroll
            for (int r = 0; r < 4; ++r) {
                long row = m0 + wm*64 + mi*16 + lq*4 + r;
                long col = n0 + wn*64 + ni*16 + lr;
                bstore(C + row*512 + col, acc[mi][ni][r]);
            }
}

// ---------------- scan pass 1: 128-thread blocks (2x occupancy), 8 states in regs ----------------
// grid (NCH, 16, 2), 128 threads; thread handles channel i = z2*128 + tid
__global__ __launch_bounds__(128) void k_scan1(const bf16* __restrict__ delta,
                                               const float* __restrict__ btct,
                                               const bf16* __restrict__ xbc,
                                               const float* __restrict__ a2,
                                               float* __restrict__ P,
                                               float* __restrict__ Q) {
    __shared__ float bts[CHUNK][8];
    int z = blockIdx.y;
    int d = z >> 3, b = z & 7;
    int c = blockIdx.x;
    int i = blockIdx.z*128 + threadIdx.x;
    // stage bt for this chunk: CHUNK*8 floats, 128 threads -> 4 each
    #pragma unroll
    for (int q = 0; q < (CHUNK*8)/128; ++q) {
        int t2 = q*128 + threadIdx.x;
        int tt = t2 >> 3, s = t2 & 7;
        int t = c*CHUNK + tt;
        long l = d ? (LL-1-t) : t;
        long row = (long)b*LL + l;
        bts[tt][s] = btct[(long)d*MM*16 + row*16 + s];
    }
    // per-channel decay coefficients
    const float* ap = a2 + ((long)d*II + i)*8;
    float4 aA = *(const float4*)(ap);
    float4 aB = *(const float4*)(ap + 4);
    float a2r[8] = {aA.x, aA.y, aA.z, aA.w, aB.x, aB.y, aB.z, aB.w};
    __syncthreads();

    int t0 = c*CHUNK;
    long l0 = d ? (long)(LL-1-t0) : (long)t0;
    long row0 = (long)b*LL + l0;
    long step = (d ? -1l : 1l) * II;
    const bf16* pd = delta + (long)d*MM*II + row0*II + i;
    const bf16* px = xbc   + (long)d*MM*II + row0*II + i;

    float Pv[8], Qv[8];
    #pragma unroll
    for (int s = 0; s < 8; ++s) { Pv[s] = 1.f; Qv[s] = 0.f; }

    float dv = bload(pd), xv = bload(px);
    for (int tt = 0; tt < CHUNK; ++tt) {
        float dvn = 0.f, xvn = 0.f;
        if (tt + 1 < CHUNK) { dvn = bload(pd + step); xvn = bload(px + step); }
        pd += step; px += step;
        float4 b0 = *(const float4*)&bts[tt][0];
        float4 b1 = *(const float4*)&bts[tt][4];
        float btv[8] = {b0.x, b0.y, b0.z, b0.w, b1.x, b1.y, b1.z, b1.w};
        #pragma unroll
        for (int s = 0; s < 8; ++s) {
            float dec = __builtin_amdgcn_fmed3f(exp2f(dv*a2r[s]), 1e-4f, 1.0f);
            Pv[s] *= dec;
            Qv[s] = fmaf(dec, Qv[s], (1.f - dec)*btv[s]*xv);
        }
        dv = dvn; xv = xvn;
    }
    long o = ((long)z*NCH + c)*2048 + (long)i*8;
    *(floatx4*)(P + o)     = (floatx4){Pv[0], Pv[1], Pv[2], Pv[3]};
    *(floatx4*)(P + o + 4) = (floatx4){Pv[4], Pv[5], Pv[6], Pv[7]};
    *(floatx4*)(Q + o)     = (floatx4){Qv[0], Qv[1], Qv[2], Qv[3]};
    *(floatx4*)(Q + o + 4) = (floatx4){Qv[4], Qv[5], Qv[6], Qv[7]};
}

// ---------------- scan pass 2 (unroll-4 batched loads: latency /4) ----------------
__global__ __launch_bounds__(256) void k_scan2(const float* __restrict__ P,
                                               const float* __restrict__ Q,
                                               float* __restrict__ sinb) {
    int d = blockIdx.y;
    long idx = (long)blockIdx.x*256 + threadIdx.x;
    int b = (int)(idx >> 11); int rem = (int)(idx & 2047);
    long base = ((long)(d*8 + b)*NCH)*2048 + rem;
    float st = 0.f;
    #pragma unroll 1
    for (int c = 0; c < NCH; c += 4) {
        long o0 = base + (long)c*2048;
        long o1 = o0 + 2048, o2 = o0 + 4096, o3 = o0 + 6144;
        float p0 = P[o0], p1 = P[o1], p2 = P[o2], p3 = P[o3];
        float q0 = Q[o0], q1 = Q[o1], q2 = Q[o2], q3 = Q[o3];
        sinb[o0] = st; st = fmaf(p0, st, q0);
        sinb[o1] = st; st = fmaf(p1, st, q1);
        sinb[o2] = st; st = fmaf(p2, st, q2);
        sinb[o3] = st; st = fmaf(p3, st, q3);
    }
}

// ---------------- scan pass 3: 128-thread blocks (2x occupancy), in-reg s-reduction ----------------
// grid (NCH, 16, 2), 128 threads
__global__ __launch_bounds__(128) void k_scan3(const bf16* __restrict__ delta,
                                               const float* __restrict__ btct,
                                               const bf16* __restrict__ xbc,
                                               const float* __restrict__ a2,
                                               const float* __restrict__ Dp,
                                               const float* __restrict__ sinb,
                                               bf16* __restrict__ u0,
                                               bf16* __restrict__ u1) {
    __shared__ float bcs[CHUNK][16];    // [t][0..7]=bt, [t][8..15]=ct
    int z = blockIdx.y;
    int d = z >> 3, b = z & 7;
    int c = blockIdx.x;
    int i = blockIdx.z*128 + threadIdx.x;
    // stage bt+ct: CHUNK*16 floats = 512 float2, 128 threads -> 4 float2 each
    #pragma unroll
    for (int q = 0; q < (CHUNK*16)/256; ++q) {
        int t2 = q*128 + threadIdx.x;
        int tt = t2 >> 3, col = (t2 & 7)*2;
        int t = c*CHUNK + tt;
        long l = d ? (LL-1-t) : t;
        long row = (long)b*LL + l;
        *(float2*)&bcs[tt][col] =
            *(const float2*)(btct + (long)d*MM*16 + row*16 + col);
    }
    const float* ap = a2 + ((long)d*II + i)*8;
    float4 aA = *(const float4*)(ap);
    float4 aB = *(const float4*)(ap + 4);
    float a2r[8] = {aA.x, aA.y, aA.z, aA.w, aB.x, aB.y, aB.z, aB.w};
    float dpv = Dp[d*II + i];
    // initial states
    const float* sb = sinb + ((long)z*NCH + c)*2048 + (long)i*8;
    float4 s0 = *(const float4*)(sb);
    float4 s1 = *(const float4*)(sb + 4);
    float st[8] = {s0.x, s0.y, s0.z, s0.w, s1.x, s1.y, s1.z, s1.w};
    __syncthreads();

    int t0 = c*CHUNK;
    long l0 = d ? (long)(LL-1-t0) : (long)t0;
    long row0 = (long)b*LL + l0;
    long step = (d ? -1l : 1l) * II;
    long ustep = (d ? -1l : 1l) * 512;
    const bf16* pd = delta + (long)d*MM*II + row0*II + i;
    const bf16* px = xbc   + (long)d*MM*II + row0*II + i;
    bf16* pu = (d ? u1 : u0) + row0*512 + i;

    float dv = bload(pd), xv = bload(px);
    for (int tt = 0; tt < CHUNK; ++tt) {
        float dvn = 0.f, xvn = 0.f;
        if (tt + 1 < CHUNK) { dvn = bload(pd + step); xvn = bload(px + step); }
        pd += step; px += step;
        const float4* q4 = (const float4*)&bcs[tt][0];
        float4 b0 = q4[0], b1 = q4[1], c0 = q4[2], c1 = q4[3];
        float btv[8] = {b0.x, b0.y, b0.z, b0.w, b1.x, b1.y, b1.z, b1.w};
        float ctv[8] = {c0.x, c0.y, c0.z, c0.w, c1.x, c1.y, c1.z, c1.w};
        float pa = dpv * xv;
        #pragma unroll
        for (int s = 0; s < 8; ++s) {
            float dec = __builtin_amdgcn_fmed3f(exp2f(dv*a2r[s]), 1e-4f, 1.0f);
            st[s] = fmaf(dec, st[s], (1.f - dec)*btv[s]*xv);
            pa = fmaf(st[s], ctv[s], pa);
        }
        bstore(pu, pa);
        pu += ustep;
        dv = dvn; xv = xvn;
    }
}

// ---------------- final LN (bf16 in, wave-per-row) -> f32 output ----------------
// grid MM/4 blocks, 4 rows/block (one wave each), no barriers
__global__ __launch_bounds__(256) void k_ln_out(const bf16* __restrict__ mixed,
                                                const float* __restrict__ w,
                                                const float* __restrict__ b,
                                                float* __restrict__ out) {
    long row = (long)blockIdx.x*4 + (threadIdx.x >> 6);
    int lane = threadIdx.x & 63;
    const bf16* mr = mixed + row*DDD;
    ushort4 ua = *(const ushort4*)(mr + lane*4);
    ushort4 ub = *(const ushort4*)(mr + 256 + lane*4);
    float v[8] = {b2f(ua.x), b2f(ua.y), b2f(ua.z), b2f(ua.w),
                  b2f(ub.x), b2f(ub.y), b2f(ub.z), b2f(ub.w)};
    float s = 0.f, q = 0.f;
    #pragma unroll
    for (int j = 0; j < 8; ++j) { s += v[j]; q += v[j]*v[j]; }
    float mean, rstd;
    wave_mean_rstd(s, q, mean, rstd);
    float4 w0 = *(const float4*)(w + lane*4), w1 = *(const float4*)(w + 256 + lane*4);
    float4 c0 = *(const float4*)(b + lane*4), c1 = *(const float4*)(b + 256 + lane*4);
    float4 o0 = {(v[0]-mean)*rstd*w0.x + c0.x, (v[1]-mean)*rstd*w0.y + c0.y,
                 (v[2]-mean)*rstd*w0.z + c0.z, (v[3]-mean)*rstd*w0.w + c0.w};
    float4 o1 = {(v[4]-mean)*rstd*w1.x + c1.x, (v[5]-mean)*rstd*w1.y + c1.y,
                 (v[6]-mean)*rstd*w1.z + c1.z, (v[7]-mean)*rstd*w1.w + c1.w};
    *(float4*)(out + row*DDD + lane*4) = o0;
    *(float4*)(out + row*DDD + 256 + lane*4) = o1;
}

extern "C" void kernel_launch(void* const* d_in, const int* in_sizes, int n_in,
                              void* d_out, int out_size, void* d_ws, size_t ws_size,
                              hipStream_t stream) {
    const float* x        = (const float*)d_in[0];
    const float* position = (const float*)d_in[1];
    const float* ln_in_w  = (const float*)d_in[2];
    const float* ln_in_b  = (const float*)d_in[3];
    const float* pos_w1   = (const float*)d_in[4];
    const float* pos_b1   = (const float*)d_in[5];
    const float* pos_w2   = (const float*)d_in[6];
    const float* pos_b2   = (const float*)d_in[7];
    const float* in_w     = (const float*)d_in[8];
    const float* cx_w     = (const float*)d_in[9];
    const float* cz_w     = (const float*)d_in[10];
    const float* xp_w     = (const float*)d_in[11];
    const float* dt_w     = (const float*)d_in[12];
    const float* dt_b     = (const float*)d_in[13];
    const float* Alog     = (const float*)d_in[14];
    const float* Dp       = (const float*)d_in[15];
    const float* out_w    = (const float*)d_in[16];
    const float* mix_w    = (const float*)d_in[17];
    const float* ln_out_w = (const float*)d_in[18];
    const float* ln_out_b = (const float*)d_in[19];
    float* out = (float*)d_out;

    char* base = (char*)d_ws;
    bf16*  si     = (bf16*)(base + WS_SI);
    bf16*  u0     = (bf16*)(base + WS_U0);
    bf16*  u1     = (bf16*)(base + WS_U1);
    bf16*  xz     = (bf16*)(base + WS_XZ);
    bf16*  H      = (bf16*)(base + WS_H);
    float* Pb     = (float*)(base + WS_P);
    float* Qb     = (float*)(base + WS_Q);
    float* sinb   = (float*)(base + WS_SINB);
    bf16*  xbc    = (bf16*)(base + WS_XBC);
    bf16*  delta  = (bf16*)(base + WS_DELTA);
    bf16*  xb16   = (bf16*)(base + WS_DELTA);   // early alias (disjoint lifetime)
    float* btct   = (float*)(base + WS_BTCT);
    bf16*  mixed  = (bf16*)(base + WS_MIXED);
    bf16*  in_wb  = (bf16*)(base + WS_INWB);
    bf16*  mix_wb = (bf16*)(base + WS_MIXWB);
    bf16*  pw2b   = (bf16*)(base + WS_PW2B);
    bf16*  owT    = (bf16*)(base + WS_OWT);
    bf16*  Wp     = (bf16*)(base + WS_WP);
    bf16*  Wd     = (bf16*)(base + WS_WD);
    bf16*  xpwb   = (bf16*)(base + WS_XPWB);
    float* a2     = (float*)(base + WS_A2);
    float* wxT    = (float*)(base + WS_WXT);
    float* wzT    = (float*)(base + WS_WZT);
    float* mrs    = (float*)(base + WS_MRS);
    float* lnbp   = (float*)(base + WS_LNBP);

    // 0. merged prep: x stats + xb16, H, owT, mix_wb, in_wb, Wd, pw2b, xpwb, a2, wT, lnbp
    k_prep<<<16248, 256, 0, stream>>>(x, mrs, xb16, ln_in_b, pos_b2, lnbp,
                                      position, pos_w1, pos_b1, H,
                                      out_w, owT, mix_w, mix_wb, in_w, in_wb,
                                      dt_w, xp_w, Wd, pos_w2, pw2b, xpwb,
                                      Alog, a2, cx_w, cz_w, wxT, wzT);
    // W'[d] = mix_w[:, d*512:] @ owT[d]^T  (merged via blockIdx.z)
    gemm_mfma<bf16, 0><<<dim3(4, 4, 2), 256, 0, stream>>>(
        mix_wb, 1536, owT, 512, Wp, 512, 512, nullptr, 512, 262144, 262144, 0,
        nullptr, nullptr, nullptr, nullptr);
    // 1+2. si = (H @ pw2b^T) + LN(x)*w+b + pb2   (fused EPI=2 epilogue, bf16 x)
    gemm_mfma<bf16, 2><<<dim3(4, MM/128), 256, 0, stream>>>(
        H, 128, pw2b, 128, si, 512, 128, nullptr, 0, 0, 0, 0,
        xb16, mrs, ln_in_w, lnbp);
    // 3. in-proj
    gemm_mfma<bf16, 0><<<dim3(8, MM/128), 256, 0, stream>>>(
        si, 512, in_wb, 512, xz, 1024, 512, nullptr, 0, 0, 0, 0,
        nullptr, nullptr, nullptr, nullptr);
    // 4. conv + SiLU (4 rows/thread)
    k_conv<<<dim3(512, 2), 256, 0, stream>>>(xz, wxT, wzT, xbc, u0, u1);
    // 5a. delta[d] = clip(softplus(xbc[d] @ Wd[d]^T + dt_b[d])), both d via blockIdx.z
    gemm_mfma<bf16, 1><<<dim3(2, MM/128, 2), 256, 0, stream>>>(
        xbc, 256, Wd, 256, delta, 256, 256, dt_b,
        (long)MM*II, 65536, (long)MM*II, 256,
        nullptr, nullptr, nullptr, nullptr);
    // 5b. btct = tanh(xbc @ xpwb^T)
    k_btct<<<dim3(MM/64, 2), 256, 0, stream>>>(xbc, xpwb, btct);
    // 6. chunked scan (CHUNK=64; 128-thread blocks, 2 channel-slabs -> 2x occupancy)
    k_scan1<<<dim3(NCH, 16, 2), 128, 0, stream>>>(delta, btct, xbc, a2, Pb, Qb);
    k_scan2<<<dim3(64, 2), 256, 0, stream>>>(Pb, Qb, sinb);
    k_scan3<<<dim3(NCH, 16, 2), 128, 0, stream>>>(delta, btct, xbc, a2, Dp,
                                                  sinb, u0, u1);
    // 7. mixed = u0@W'0^T + u1@W'1^T + si@Wm2^T  (bf16 out)
    gemm_mix3<<<dim3(4, MM/128), 256, 0, stream>>>(u0, u1, si,
                                                   Wp, Wp + 262144, mix_wb + 1024, 1536,
                                                   mixed);
    // 8. out = LN(mixed)  (wave-per-row, 4 rows/block)
    k_ln_out<<<MM/4, 256, 0, stream>>>(mixed, ln_out_w, ln_out_b, out);
}

// Round 14
// 324.328 us; speedup vs baseline: 1.0663x; 1.0663x over previous
//
#include <hip/hip_runtime.h>
#include <hip/hip_bf16.h>

typedef __hip_bfloat16 bf16;
typedef __attribute__((ext_vector_type(8))) short short8;
typedef __attribute__((ext_vector_type(4))) float floatx4;

#define BBB 8
#define LL 2048
#define DDD 512
#define II 256
#define SS 8
#define MM (BBB*LL)      // 16384 rows
#define CHUNK 64
#define NCH (LL/CHUNK)   // 32

// ---- workspace (bytes); proven ws_size >= 131,072,000 ----
#define WS_SI    0l          // si bf16 [M,512]            -> 16,777,216
#define WS_U0    16777216l   // u0 bf16 [M,512] (y0|zb0)   -> 33,554,432
#define WS_U1    33554432l   // u1 bf16 [M,512] (y1|zb1)   -> 50,331,648
#define WS_XZ    50331648l   // xz bf16 [M,1024]           -> 83,886,080
//   XZ region reuse (disjoint lifetimes):
#define WS_H     67108864l   // H bf16 [M,128] (early)           -> +4,194,304
#define WS_P     50331648l   // P f32 [16][32][2048] (after conv)-> +4,194,304
#define WS_Q     58720256l   // Q f32                            -> +4,194,304
#define WS_SINB  67108864l   // sinb f32                         -> +4,194,304
#define WS_XBC   83886080l   // xbc bf16 [2][M,256]        -> 100,663,296
#define WS_MIXED 83886080l   // mixed bf16 [M,512] (alias xbc, after scan)
#define WS_DELTA 100663296l  // delta bf16 [2][M,256]      -> 117,440,512
//   DELTA region reuse: xb16 bf16 [M,512] (early: prep -> posout GEMM)
#define WS_BTCT  117440512l  // btct f32 [2][M,16]         -> 121,634,816
#define WS_INWB  121634816l  // in_w  bf16 [1024,512]      -> 122,683,392
#define WS_MIXWB 122683392l  // mix_w bf16 [512,1536]      -> 124,256,256
#define WS_PW2B  124256256l  // pos_w2 bf16 [512,128]      -> 124,387,328
#define WS_OWT   124387328l  // out_w^T bf16 [2][512,512]  -> 125,435,904
#define WS_WP    125435904l  // W' bf16 [2][512,512]       -> 126,484,480
#define WS_WD    126484480l  // Wd bf16 [2][256][256]      -> 126,746,624
#define WS_XPWB  126746624l  // xp_w[32:48] bf16 [2][16][256] -> 126,763,008
#define WS_A2    126763008l  // a2 f32 [2][256][8]         -> 126,779,392
#define WS_WXT   126779392l  // wxT f32 [2][3][256] (k pre-flipped for d=1) -> 126,785,536
#define WS_WZT   126785536l  // wzT f32 [2][3][256] (k pre-flipped for d=1) -> 126,791,680
#define WS_MRS   126791680l  // mrs f32 [M][2] (mean,rstd of x rows) -> 126,922,752
#define WS_LNBP  126922752l  // lnbp f32 [512] = ln_in_b + pos_b2    -> 126,924,800

// ---------------- helpers ----------------
__device__ __forceinline__ float b2f(unsigned short u) {
    return __uint_as_float(((unsigned)u) << 16);
}
__device__ __forceinline__ float bload(const bf16* p) {
    return b2f(*(const unsigned short*)p);
}
__device__ __forceinline__ void bstore(bf16* p, float v) {
    *p = __float2bfloat16(v);
}
__device__ __forceinline__ float softplus_f(float x) {
    return fmaxf(x, 0.f) + log1pf(expf(-fabsf(x)));
}
__device__ __forceinline__ float silu_f(float x) {
    return x / (1.f + expf(-x));
}
// async global->LDS, 16 bytes per lane; LDS dest is wave-uniform base + lane*16
__device__ __forceinline__ void gl_lds16(const bf16* g, void* l) {
    __builtin_amdgcn_global_load_lds(
        (const __attribute__((address_space(1))) unsigned int*)g,
        (__attribute__((address_space(3))) unsigned int*)l, 16, 0, 0);
}
// counted-vmcnt pipeline primitives (T4): barrier-after-own-vmcnt = collective wait
#define VMWAIT_N(n) asm volatile("s_waitcnt vmcnt(" #n ")" ::: "memory")
#define VMWAIT0() asm volatile("s_waitcnt vmcnt(0)" ::: "memory")
#define XBAR()    __builtin_amdgcn_s_barrier()

// wave-level (64-lane) mean/rstd: xor butterfly, all lanes get result, no barriers
__device__ __forceinline__ void wave_mean_rstd(float s, float q,
                                               float& mean, float& rstd) {
    #pragma unroll
    for (int off = 1; off < 64; off <<= 1) {
        s += __shfl_xor(s, off);
        q += __shfl_xor(q, off);
    }
    mean = s * (1.f/DDD);
    float var = q * (1.f/DDD) - mean*mean;
    rstd = rsqrtf(var + 1e-6f);
}

// ---------------- merged prep kernel ----------------
// sections by blockIdx.x:
// [0,4096) x row stats (wave-per-row, 4 rows/block) + x->bf16
// [4096,12288) k_h | [12288,14336) tow | [14336,15104) f2b mix
// [15104,15616) f2b in_w | [15616,16128) wd | [16128,16192) f2b pos_w2
// [16192,16224) xpw16 | [16224,16240) aprep | [16240,16246) wt | [16246,16248) lnbp
__global__ __launch_bounds__(256)
void k_prep(const float* __restrict__ x, float* __restrict__ mrs,
            bf16* __restrict__ xb16,
            const float* __restrict__ lnb, const float* __restrict__ pb2,
            float* __restrict__ lnbp,
            const float* __restrict__ position, const float* __restrict__ pw1,
            const float* __restrict__ pb1, bf16* __restrict__ H,
            const float* __restrict__ ow, bf16* __restrict__ owT,
            const float* __restrict__ mixw, bf16* __restrict__ mixwb,
            const float* __restrict__ inw, bf16* __restrict__ inwb,
            const float* __restrict__ dtw, const float* __restrict__ xpw,
            bf16* __restrict__ Wd,
            const float* __restrict__ posw2, bf16* __restrict__ pw2b,
            bf16* __restrict__ xpwb,
            const float* __restrict__ Alog, float* __restrict__ a2,
            const float* __restrict__ cxw, const float* __restrict__ czw,
            float* __restrict__ wxT, float* __restrict__ wzT) {
    int bb = blockIdx.x;
    int tid = threadIdx.x;
    if (bb < 4096) {                     // x row stats + bf16 copy (wave-per-row)
        long row = (long)bb*4 + (tid >> 6);
        int lane = tid & 63;
        const float* xr = x + row*DDD;
        float4 a = *(const float4*)(xr + lane*4);
        float4 c = *(const float4*)(xr + 256 + lane*4);
        bf16 t0[4] = {__float2bfloat16(a.x), __float2bfloat16(a.y),
                      __float2bfloat16(a.z), __float2bfloat16(a.w)};
        bf16 t1[4] = {__float2bfloat16(c.x), __float2bfloat16(c.y),
                      __float2bfloat16(c.z), __float2bfloat16(c.w)};
        *(ushort4*)(xb16 + row*DDD + lane*4)       = *(ushort4*)t0;
        *(ushort4*)(xb16 + row*DDD + 256 + lane*4) = *(ushort4*)t1;
        float s = a.x+a.y+a.z+a.w + c.x+c.y+c.z+c.w;
        float q = a.x*a.x+a.y*a.y+a.z*a.z+a.w*a.w
                + c.x*c.x+c.y*c.y+c.z*c.z+c.w*c.w;
        float mean, rstd;
        wave_mean_rstd(s, q, mean, rstd);
        if (lane == 0) { mrs[row*2] = mean; mrs[row*2+1] = rstd; }
    } else if (bb < 12288) {             // H = gelu(position @ pw1^T + pb1)
        long idx = (long)(bb - 4096)*256 + tid;
        long row = idx >> 7; int ph = idx & 127;
        const float* p = position + row*6;
        const float* w = pw1 + ph*6;
        float v = pb1[ph];
        #pragma unroll
        for (int j = 0; j < 6; ++j) v = fmaf(p[j], w[j], v);
        v = 0.5f * v * (1.f + erff(v * 0.70710678118654752440f));
        bstore(H + idx, v);
    } else if (bb < 14336) {             // owT[d][k][c] = out_w[d][c][k]
        long idx = (long)(bb - 12288)*256 + tid;
        long d = idx >> 18; long rem = idx & 262143;
        long k = rem >> 9, c = rem & 511;
        bstore(owT + idx, ow[d*262144 + c*512 + k]);
    } else if (bb < 15104) {             // f2b mix_w (786432)
        int i = (bb - 14336)*256*4 + tid*4;
        float4 v = *(const float4*)(mixw + i);
        bf16 t[4] = {__float2bfloat16(v.x), __float2bfloat16(v.y),
                     __float2bfloat16(v.z), __float2bfloat16(v.w)};
        *(ushort4*)(mixwb + i) = *(ushort4*)t;
    } else if (bb < 15616) {             // f2b in_w (524288)
        int i = (bb - 15104)*256*4 + tid*4;
        float4 v = *(const float4*)(inw + i);
        bf16 t[4] = {__float2bfloat16(v.x), __float2bfloat16(v.y),
                     __float2bfloat16(v.z), __float2bfloat16(v.w)};
        *(ushort4*)(inwb + i) = *(ushort4*)t;
    } else if (bb < 16128) {             // Wd[d] = dt_w[d] @ xp_w[d][:32,:]
        int local = bb - 15616;
        int d = local >> 8, i = local & 255, j = tid;
        const float* wr = dtw + (long)d*II*32 + i*32;
        const float* xp = xpw + (long)d*48*II;
        float acc = 0.f;
        #pragma unroll
        for (int k = 0; k < 32; ++k) acc = fmaf(wr[k], xp[k*II + j], acc);
        bstore(Wd + ((long)d*II + i)*II + j, acc);
    } else if (bb < 16192) {             // f2b pos_w2 (65536)
        int i = (bb - 16128)*256*4 + tid*4;
        float4 v = *(const float4*)(posw2 + i);
        bf16 t[4] = {__float2bfloat16(v.x), __float2bfloat16(v.y),
                     __float2bfloat16(v.z), __float2bfloat16(v.w)};
        *(ushort4*)(pw2b + i) = *(ushort4*)t;
    } else if (bb < 16224) {             // xpwb (8192)
        int idx = (bb - 16192)*256 + tid;
        int d = idx >> 12, rem = idx & 4095;
        bstore(xpwb + idx, xpw[(long)d*48*II + 32*II + rem]);
    } else if (bb < 16240) {             // a2 (4096)
        int idx = (bb - 16224)*256 + tid;
        float a = softplus_f(Alog[idx]) + 1e-4f;
        a2[idx] = -1.4426950408889634f * a;
    } else if (bb < 16246) {             // conv weight transpose (1536)
        int idx = (bb - 16240)*256 + tid;
        if (idx < 1536) {
            int d = idx / 768, rem = idx % 768;
            int k = rem >> 8, i = rem & 255;
            int kk = d ? (2 - k) : k;
            wxT[idx] = cxw[d*768 + i*3 + kk];
            wzT[idx] = czw[d*768 + i*3 + kk];
        }
    } else {                             // lnbp (512)
        int idx = (bb - 16246)*256 + tid;
        lnbp[idx] = lnb[idx] + pb2[idx];
    }
}

// ---- shared GEMM body macro; expects KKN, MASKC, wm/wn/lr/lq, acc in scope ----
#define GEMM_COMPUTE(Sa, Sb)                                                      \
    do {                                                                          \
        _Pragma("unroll")                                                         \
        for (int kk = 0; kk < KKN; ++kk) {                                        \
            const int sa_ = ((kk*4 + lq) ^ (lr & MASKC)) * 16;                    \
            short8 af[4], bfr[4];                                                 \
            _Pragma("unroll")                                                     \
            for (int mi = 0; mi < 4; ++mi)                                        \
                af[mi] = *(const short8*)((const char*)&Sa[wm*64 + mi*16 + lr][0] + sa_); \
            _Pragma("unroll")                                                     \
            for (int ni = 0; ni < 4; ++ni)                                        \
                bfr[ni] = *(const short8*)((const char*)&Sb[wn*64 + ni*16 + lr][0] + sa_); \
            _Pragma("unroll")                                                     \
            for (int mi = 0; mi < 4; ++mi)                                        \
                _Pragma("unroll")                                                 \
                for (int ni = 0; ni < 4; ++ni)                                    \
                    acc[mi][ni] = __builtin_amdgcn_mfma_f32_16x16x32_bf16(        \
                        af[mi], bfr[ni], acc[mi][ni], 0, 0, 0);                   \
        }                                                                         \
    } while (0)

// ---------------- pipelined MFMA GEMM: C[M,N] = A[M,K] @ B^T ----------------
// BK=64. Depth-2 prefetch, counted vmcnt(8) + raw s_barrier (T4), static
// buffer names, XOR-swizzled LDS via pre-swizzled global source, XCD swizzle.
// Kdim must be a multiple of 128 (NT even) -- true at all call sites.
// EPI 0: plain store; EPI 1: clip(softplus(v+bias[col]));
// EPI 2: v += (xb16[row,col]-mean[row])*rstd[row]*lnw[col] + lnbp[col]
template<typename TC, int EPI = 0>
__global__ __launch_bounds__(256)
void gemm_mfma(const bf16* __restrict__ A, long lda,
               const bf16* __restrict__ B, long ldb,
               TC* __restrict__ C, long ldc, int Kdim,
               const float* __restrict__ bias,
               long zA, long zB, long zC, long zbias,
               const bf16* __restrict__ xb16, const float* __restrict__ mrs,
               const float* __restrict__ lnw, const float* __restrict__ lnbp) {
    enum { KKN = 2, MASKC = 7 };
    __shared__ short As0[128][64], Bs0[128][64];
    __shared__ short As1[128][64], Bs1[128][64];
    const int tid = threadIdx.x;
    const int lane = tid & 63;
    const int wave = tid >> 6;
    const int wm = wave >> 1, wn = wave & 1;
    const int lr = lane & 15, lq = lane >> 4;
    A += (long)blockIdx.z * zA;
    B += (long)blockIdx.z * zB;
    C += (long)blockIdx.z * zC;
    const float* bp = bias ? bias + (long)blockIdx.z * zbias : nullptr;
    // XCD-aware swizzle (all call sites have nwg % 8 == 0)
    int nwg = gridDim.x * gridDim.y;
    int bid = blockIdx.y * gridDim.x + blockIdx.x;
    int wg = (bid & 7) * (nwg >> 3) + (bid >> 3);
    const long m0 = (long)(wg / gridDim.x) * 128;
    const long n0 = (long)(wg % gridDim.x) * 128;

    // staging descriptors: LDS chunk ch = r*8+c holds global chunk (r, c^(r&7))
    const bf16* gA[4]; const bf16* gB[4]; int off16[4];
    #pragma unroll
    for (int q = 0; q < 4; ++q) {
        int ch = q*256 + tid;
        int r = ch >> 3;
        int g = (ch & 7) ^ (r & 7);
        gA[q] = A + (m0 + r)*lda + g*8;
        gB[q] = B + (n0 + r)*ldb + g*8;
        off16[q] = (q*256 + wave*64) * 16;   // wave-uniform LDS byte base
    }
#define STAGE_G(Sa, Sb, k0)                                   \
    do {                                                      \
        _Pragma("unroll")                                     \
        for (int q = 0; q < 4; ++q) {                         \
            gl_lds16(gA[q] + (k0), (char*)(Sa) + off16[q]);   \
            gl_lds16(gB[q] + (k0), (char*)(Sb) + off16[q]);   \
        }                                                     \
    } while (0)

    floatx4 acc[4][4];
    #pragma unroll
    for (int i = 0; i < 4; ++i)
        #pragma unroll
        for (int j = 0; j < 4; ++j)
            acc[i][j] = (floatx4){0.f, 0.f, 0.f, 0.f};

    const int NT = Kdim >> 6;
    STAGE_G(As0, Bs0, 0);
    STAGE_G(As1, Bs1, 64);
    int t = 0;
    for (; t + 2 < NT; t += 2) {
        VMWAIT_N(8); XBAR();                     // S0 tile ready (collective)
        GEMM_COMPUTE(As0, Bs0);
        XBAR();                                  // all reads of S0 done
        STAGE_G(As0, Bs0, (long)(t + 2) << 6);
        VMWAIT_N(8); XBAR();                     // S1 tile ready
        GEMM_COMPUTE(As1, Bs1);
        XBAR();
        STAGE_G(As1, Bs1, (long)(t + 3) << 6);
    }
    VMWAIT_N(8); XBAR();
    GEMM_COMPUTE(As0, Bs0);
    VMWAIT0(); XBAR();
    GEMM_COMPUTE(As1, Bs1);
#undef STAGE_G
    #pragma unroll
    for (int mi = 0; mi < 4; ++mi)
        #pragma unroll
        for (int ni = 0; ni < 4; ++ni)
            #pragma unroll
            for (int r = 0; r < 4; ++r) {
                long row = m0 + wm*64 + mi*16 + lq*4 + r;
                long col = n0 + wn*64 + ni*16 + lr;
                float v = acc[mi][ni][r];
                if (EPI == 1)
                    v = fminf(fmaxf(softplus_f(v + bp[col]), 1e-4f), 1.0f);
                if (EPI == 2) {
                    float2 ms = *(const float2*)(mrs + row*2);
                    v += (bload(xb16 + row*512 + col) - ms.x)*ms.y*lnw[col] + lnbp[col];
                }
                if constexpr (sizeof(TC) == 2) bstore((bf16*)C + row*ldc + col, v);
                else ((float*)C)[row*ldc + col] = v;
            }
}

// ---------------- btct: tanh(xbc @ xpwb^T) -> f32 [2][M,16]; per-wave 16x16 tile ----------------
__global__ __launch_bounds__(256) void k_btct(const bf16* __restrict__ xbc,
                                              const bf16* __restrict__ xpwb,
                                              float* __restrict__ btct) {
    int d = blockIdx.y;
    int wave = threadIdx.x >> 6, lane = threadIdx.x & 63;
    long r0 = (long)blockIdx.x*64 + wave*16;
    int lr = lane & 15, lq = lane >> 4;
    const bf16* xb = xbc  + (long)d*MM*II;
    const bf16* wp = xpwb + (long)d*16*II;
    floatx4 acc = (floatx4){0.f, 0.f, 0.f, 0.f};
    #pragma unroll
    for (int k0 = 0; k0 < II; k0 += 32) {
        short8 af = *(const short8*)(xb + (r0 + lr)*II + k0 + lq*8);
        short8 bf = *(const short8*)(wp + lr*II + k0 + lq*8);
        acc = __builtin_amdgcn_mfma_f32_16x16x32_bf16(af, bf, acc, 0, 0, 0);
    }
    #pragma unroll
    for (int r = 0; r < 4; ++r) {
        long row = r0 + lq*4 + r;
        btct[((long)d*MM + row)*16 + lr] = tanhf(acc[r]);
    }
}

// ---------------- depthwise conv3 + SiLU (8 ch x 4 rows per thread) ----------------
// grid (512, 2): idx over MM/4 row-groups x 32 channel-groups
__global__ __launch_bounds__(256) void k_conv(const bf16* __restrict__ xz,
                                              const float* __restrict__ wxT,
                                              const float* __restrict__ wzT,
                                              bf16* __restrict__ xbc,
                                              bf16* __restrict__ u0,
                                              bf16* __restrict__ u1) {
    int d = blockIdx.y;
    long idx = (long)blockIdx.x*256 + threadIdx.x;   // over (MM/4)*32 = 131072
    long rg = idx >> 5; int i = (int)(idx & 31) * 8;
    long row0 = rg << 2;
    int l0 = (int)(row0 & (LL-1));                    // multiple of 4
    // weights for this thread's 8 channels: 12 coalesced float4 loads, k pre-flipped
    const float* wxp = wxT + d*768 + i;
    const float* wzp = wzT + d*768 + i;
    float wxr[3][8], wzr[3][8];
    #pragma unroll
    for (int k = 0; k < 3; ++k) {
        *(float4*)&wxr[k][0] = *(const float4*)(wxp + k*256);
        *(float4*)&wxr[k][4] = *(const float4*)(wxp + k*256 + 4);
        *(float4*)&wzr[k][0] = *(const float4*)(wzp + k*256);
        *(float4*)&wzr[k][4] = *(const float4*)(wzp + k*256 + 4);
    }
    const bf16* base = xz + row0*1024 + (long)d*512 + i;
    short8 X[6], Z[6];
    #pragma unroll
    for (int k = 0; k < 6; ++k) {
        int gl = l0 - 1 + k;
        bool ok = (gl >= 0) && (gl < LL);
        if (ok) {
            X[k] = *(const short8*)(base + (long)(k-1)*1024);
            Z[k] = *(const short8*)(base + (long)(k-1)*1024 + 256);
        } else {
            X[k] = (short8){0,0,0,0,0,0,0,0};
            Z[k] = (short8){0,0,0,0,0,0,0,0};
        }
    }
    bf16* u = d ? u1 : u0;
    #pragma unroll
    for (int r = 0; r < 4; ++r) {
        bf16 ox[8], oz[8];
        #pragma unroll
        for (int j = 0; j < 8; ++j) {
            float ax = 0.f, az = 0.f;
            #pragma unroll
            for (int k = 0; k < 3; ++k) {
                ax = fmaf(b2f((unsigned short)X[r+k][j]), wxr[k][j], ax);
                az = fmaf(b2f((unsigned short)Z[r+k][j]), wzr[k][j], az);
            }
            ox[j] = __float2bfloat16(silu_f(ax));
            oz[j] = __float2bfloat16(silu_f(az));
        }
        *(short8*)(xbc + (long)d*MM*II + (row0+r)*II + i) = *(short8*)ox;
        *(short8*)(u + (row0+r)*512 + 256 + i) = *(short8*)oz;
    }
}

// ---------------- pipelined segmented GEMM: mixed = [A0|A1|A2] @ [B0|B1|B2]^T -> bf16 ----------------
__global__ __launch_bounds__(256)
void gemm_mix3(const bf16* __restrict__ A0, const bf16* __restrict__ A1,
               const bf16* __restrict__ A2,
               const bf16* __restrict__ B0, const bf16* __restrict__ B1,
               const bf16* __restrict__ B2, long ldb2,
               bf16* __restrict__ C) {
    enum { KKN = 2, MASKC = 7 };
    __shared__ short As0[128][64], Bs0[128][64];
    __shared__ short As1[128][64], Bs1[128][64];
    const int tid = threadIdx.x;
    const int lane = tid & 63;
    const int wave = tid >> 6;
    const int wm = wave >> 1, wn = wave & 1;
    const int lr = lane & 15, lq = lane >> 4;
    int nwg = gridDim.x * gridDim.y;
    int bid = blockIdx.y * gridDim.x + blockIdx.x;
    int wg = (bid & 7) * (nwg >> 3) + (bid >> 3);
    const long m0 = (long)(wg / gridDim.x) * 128;
    const long n0 = (long)(wg % gridDim.x) * 128;

    long aoff[4], boffA[4], boffB[4]; int off16[4];
    #pragma unroll
    for (int q = 0; q < 4; ++q) {
        int ch = q*256 + tid;
        int r = ch >> 3;
        int g = (ch & 7) ^ (r & 7);
        aoff[q]  = (m0 + r)*512 + g*8;
        boffA[q] = (n0 + r)*512 + g*8;
        boffB[q] = (n0 + r)*ldb2 + g*8;
        off16[q] = (q*256 + wave*64) * 16;
    }
#define STAGE_M(Sa, Sb, t)                                                   \
    do {                                                                     \
        int seg_ = (t) >> 3;                                                 \
        long kc_ = ((long)(t) << 6) & 511;                                   \
        const bf16* Ap_ = (seg_ == 0) ? A0 : (seg_ == 1 ? A1 : A2);          \
        const bf16* Bp_ = (seg_ == 0) ? B0 : (seg_ == 1 ? B1 : B2);          \
        _Pragma("unroll")                                                    \
        for (int q = 0; q < 4; ++q) {                                        \
            gl_lds16(Ap_ + aoff[q] + kc_, (char*)(Sa) + off16[q]);           \
            gl_lds16(Bp_ + (seg_ < 2 ? boffA[q] : boffB[q]) + kc_,           \
                     (char*)(Sb) + off16[q]);                                \
        }                                                                    \
    } while (0)

    floatx4 acc[4][4];
    #pragma unroll
    for (int i = 0; i < 4; ++i)
        #pragma unroll
        for (int j = 0; j < 4; ++j)
            acc[i][j] = (floatx4){0.f, 0.f, 0.f, 0.f};

    STAGE_M(As0, Bs0, 0);
    STAGE_M(As1, Bs1, 1);
    int t = 0;
    for (; t + 2 < 24; t += 2) {
        VMWAIT_N(8); XBAR();
        GEMM_COMPUTE(As0, Bs0);
        XBAR();
        STAGE_M(As0, Bs0, t + 2);
        VMWAIT_N(8); XBAR();
        GEMM_COMPUTE(As1, Bs1);
        XBAR();
        STAGE_M(As1, Bs1, t + 3);
    }
    VMWAIT_N(8); XBAR();
    GEMM_COMPUTE(As0, Bs0);
    VMWAIT0(); XBAR();
    GEMM_COMPUTE(As1, Bs1);
#undef STAGE_M
    #pragma unroll
    for (int mi = 0; mi < 4; ++mi)
        #pragma unroll
        for (int ni = 0; ni < 4; ++ni)
            #pragma unroll
            for (int r = 0; r < 4; ++r) {
                long row = m0 + wm*64 + mi*16 + lq*4 + r;
                long col = n0 + wn*64 + ni*16 + lr;
                bstore(C + row*512 + col, acc[mi][ni][r]);
            }
}

// ---------------- scan pass 1: thread-per-channel, 8 states in registers ----------------
// grid (NCH, 16), 256 threads; thread i handles all 8 s of channel i
__global__ __launch_bounds__(256) void k_scan1(const bf16* __restrict__ delta,
                                               const float* __restrict__ btct,
                                               const bf16* __restrict__ xbc,
                                               const float* __restrict__ a2,
                                               float* __restrict__ P,
                                               float* __restrict__ Q) {
    __shared__ float bts[CHUNK][8];
    int z = blockIdx.y;
    int d = z >> 3, b = z & 7;
    int c = blockIdx.x;
    int i = threadIdx.x;
    // stage bt for this chunk: CHUNK*8 floats, 2 per thread
    #pragma unroll
    for (int q = 0; q < (CHUNK*8)/256; ++q) {
        int t2 = q*256 + threadIdx.x;
        int tt = t2 >> 3, s = t2 & 7;
        int t = c*CHUNK + tt;
        long l = d ? (LL-1-t) : t;
        long row = (long)b*LL + l;
        bts[tt][s] = btct[(long)d*MM*16 + row*16 + s];
    }
    // per-channel decay coefficients
    const float* ap = a2 + ((long)d*II + i)*8;
    float4 aA = *(const float4*)(ap);
    float4 aB = *(const float4*)(ap + 4);
    float a2r[8] = {aA.x, aA.y, aA.z, aA.w, aB.x, aB.y, aB.z, aB.w};
    __syncthreads();

    int t0 = c*CHUNK;
    long l0 = d ? (long)(LL-1-t0) : (long)t0;
    long row0 = (long)b*LL + l0;
    long step = (d ? -1l : 1l) * II;
    const bf16* pd = delta + (long)d*MM*II + row0*II + i;
    const bf16* px = xbc   + (long)d*MM*II + row0*II + i;

    float Pv[8], Qv[8];
    #pragma unroll
    for (int s = 0; s < 8; ++s) { Pv[s] = 1.f; Qv[s] = 0.f; }

    float dv = bload(pd), xv = bload(px);
    for (int tt = 0; tt < CHUNK; ++tt) {
        float dvn = 0.f, xvn = 0.f;
        if (tt + 1 < CHUNK) { dvn = bload(pd + step); xvn = bload(px + step); }
        pd += step; px += step;
        float4 b0 = *(const float4*)&bts[tt][0];
        float4 b1 = *(const float4*)&bts[tt][4];
        float btv[8] = {b0.x, b0.y, b0.z, b0.w, b1.x, b1.y, b1.z, b1.w};
        #pragma unroll
        for (int s = 0; s < 8; ++s) {
            float dec = __builtin_amdgcn_fmed3f(exp2f(dv*a2r[s]), 1e-4f, 1.0f);
            Pv[s] *= dec;
            Qv[s] = fmaf(dec, Qv[s], (1.f - dec)*btv[s]*xv);
        }
        dv = dvn; xv = xvn;
    }
    long o = ((long)z*NCH + c)*2048 + (long)i*8;
    *(floatx4*)(P + o)     = (floatx4){Pv[0], Pv[1], Pv[2], Pv[3]};
    *(floatx4*)(P + o + 4) = (floatx4){Pv[4], Pv[5], Pv[6], Pv[7]};
    *(floatx4*)(Q + o)     = (floatx4){Qv[0], Qv[1], Qv[2], Qv[3]};
    *(floatx4*)(Q + o + 4) = (floatx4){Qv[4], Qv[5], Qv[6], Qv[7]};
}

// ---------------- scan pass 2 (unroll-4 batched loads: latency /4) ----------------
__global__ __launch_bounds__(256) void k_scan2(const float* __restrict__ P,
                                               const float* __restrict__ Q,
                                               float* __restrict__ sinb) {
    int d = blockIdx.y;
    long idx = (long)blockIdx.x*256 + threadIdx.x;
    int b = (int)(idx >> 11); int rem = (int)(idx & 2047);
    long base = ((long)(d*8 + b)*NCH)*2048 + rem;
    float st = 0.f;
    #pragma unroll 1
    for (int c = 0; c < NCH; c += 4) {
        long o0 = base + (long)c*2048;
        long o1 = o0 + 2048, o2 = o0 + 4096, o3 = o0 + 6144;
        float p0 = P[o0], p1 = P[o1], p2 = P[o2], p3 = P[o3];
        float q0 = Q[o0], q1 = Q[o1], q2 = Q[o2], q3 = Q[o3];
        sinb[o0] = st; st = fmaf(p0, st, q0);
        sinb[o1] = st; st = fmaf(p1, st, q1);
        sinb[o2] = st; st = fmaf(p2, st, q2);
        sinb[o3] = st; st = fmaf(p3, st, q3);
    }
}

// ---------------- scan pass 3: thread-per-channel, in-register s-reduction ----------------
// grid (NCH, 16), 256 threads
__global__ __launch_bounds__(256) void k_scan3(const bf16* __restrict__ delta,
                                               const float* __restrict__ btct,
                                               const bf16* __restrict__ xbc,
                                               const float* __restrict__ a2,
                                               const float* __restrict__ Dp,
                                               const float* __restrict__ sinb,
                                               bf16* __restrict__ u0,
                                               bf16* __restrict__ u1) {
    __shared__ float bcs[CHUNK][16];    // [t][0..7]=bt, [t][8..15]=ct
    int z = blockIdx.y;
    int d = z >> 3, b = z & 7;
    int c = blockIdx.x;
    int i = threadIdx.x;
    // stage bt+ct for this chunk: CHUNK*16 floats, float2 x (CHUNK/32) per thread
    #pragma unroll
    for (int q = 0; q < (CHUNK*16)/512; ++q) {
        int t2 = q*256 + threadIdx.x;
        int tt = t2 >> 3, col = (t2 & 7)*2;
        int t = c*CHUNK + tt;
        long l = d ? (LL-1-t) : t;
        long row = (long)b*LL + l;
        *(float2*)&bcs[tt][col] =
            *(const float2*)(btct + (long)d*MM*16 + row*16 + col);
    }
    const float* ap = a2 + ((long)d*II + i)*8;
    float4 aA = *(const float4*)(ap);
    float4 aB = *(const float4*)(ap + 4);
    float a2r[8] = {aA.x, aA.y, aA.z, aA.w, aB.x, aB.y, aB.z, aB.w};
    float dpv = Dp[d*II + i];
    // initial states
    const float* sb = sinb + ((long)z*NCH + c)*2048 + (long)i*8;
    float4 s0 = *(const float4*)(sb);
    float4 s1 = *(const float4*)(sb + 4);
    float st[8] = {s0.x, s0.y, s0.z, s0.w, s1.x, s1.y, s1.z, s1.w};
    __syncthreads();

    int t0 = c*CHUNK;
    long l0 = d ? (long)(LL-1-t0) : (long)t0;
    long row0 = (long)b*LL + l0;
    long step = (d ? -1l : 1l) * II;
    long ustep = (d ? -1l : 1l) * 512;
    const bf16* pd = delta + (long)d*MM*II + row0*II + i;
    const bf16* px = xbc   + (long)d*MM*II + row0*II + i;
    bf16* pu = (d ? u1 : u0) + row0*512 + i;

    float dv = bload(pd), xv = bload(px);
    for (int tt = 0; tt < CHUNK; ++tt) {
        float dvn = 0.f, xvn = 0.f;
        if (tt + 1 < CHUNK) { dvn = bload(pd + step); xvn = bload(px + step); }
        pd += step; px += step;
        const float4* q4 = (const float4*)&bcs[tt][0];
        float4 b0 = q4[0], b1 = q4[1], c0 = q4[2], c1 = q4[3];
        float btv[8] = {b0.x, b0.y, b0.z, b0.w, b1.x, b1.y, b1.z, b1.w};
        float ctv[8] = {c0.x, c0.y, c0.z, c0.w, c1.x, c1.y, c1.z, c1.w};
        float pa = dpv * xv;
        #pragma unroll
        for (int s = 0; s < 8; ++s) {
            float dec = __builtin_amdgcn_fmed3f(exp2f(dv*a2r[s]), 1e-4f, 1.0f);
            st[s] = fmaf(dec, st[s], (1.f - dec)*btv[s]*xv);
            pa = fmaf(st[s], ctv[s], pa);
        }
        bstore(pu, pa);
        pu += ustep;
        dv = dvn; xv = xvn;
    }
}

// ---------------- final LN (bf16 in, wave-per-row) -> f32 output ----------------
// grid MM/4 blocks, 4 rows/block (one wave each), no barriers
__global__ __launch_bounds__(256) void k_ln_out(const bf16* __restrict__ mixed,
                                                const float* __restrict__ w,
                                                const float* __restrict__ b,
                                                float* __restrict__ out) {
    long row = (long)blockIdx.x*4 + (threadIdx.x >> 6);
    int lane = threadIdx.x & 63;
    const bf16* mr = mixed + row*DDD;
    ushort4 ua = *(const ushort4*)(mr + lane*4);
    ushort4 ub = *(const ushort4*)(mr + 256 + lane*4);
    float v[8] = {b2f(ua.x), b2f(ua.y), b2f(ua.z), b2f(ua.w),
                  b2f(ub.x), b2f(ub.y), b2f(ub.z), b2f(ub.w)};
    float s = 0.f, q = 0.f;
    #pragma unroll
    for (int j = 0; j < 8; ++j) { s += v[j]; q += v[j]*v[j]; }
    float mean, rstd;
    wave_mean_rstd(s, q, mean, rstd);
    float4 w0 = *(const float4*)(w + lane*4), w1 = *(const float4*)(w + 256 + lane*4);
    float4 c0 = *(const float4*)(b + lane*4), c1 = *(const float4*)(b + 256 + lane*4);
    float4 o0 = {(v[0]-mean)*rstd*w0.x + c0.x, (v[1]-mean)*rstd*w0.y + c0.y,
                 (v[2]-mean)*rstd*w0.z + c0.z, (v[3]-mean)*rstd*w0.w + c0.w};
    float4 o1 = {(v[4]-mean)*rstd*w1.x + c1.x, (v[5]-mean)*rstd*w1.y + c1.y,
                 (v[6]-mean)*rstd*w1.z + c1.z, (v[7]-mean)*rstd*w1.w + c1.w};
    *(float4*)(out + row*DDD + lane*4) = o0;
    *(float4*)(out + row*DDD + 256 + lane*4) = o1;
}

extern "C" void kernel_launch(void* const* d_in, const int* in_sizes, int n_in,
                              void* d_out, int out_size, void* d_ws, size_t ws_size,
                              hipStream_t stream) {
    const float* x        = (const float*)d_in[0];
    const float* position = (const float*)d_in[1];
    const float* ln_in_w  = (const float*)d_in[2];
    const float* ln_in_b  = (const float*)d_in[3];
    const float* pos_w1   = (const float*)d_in[4];
    const float* pos_b1   = (const float*)d_in[5];
    const float* pos_w2   = (const float*)d_in[6];
    const float* pos_b2   = (const float*)d_in[7];
    const float* in_w     = (const float*)d_in[8];
    const float* cx_w     = (const float*)d_in[9];
    const float* cz_w     = (const float*)d_in[10];
    const float* xp_w     = (const float*)d_in[11];
    const float* dt_w     = (const float*)d_in[12];
    const float* dt_b     = (const float*)d_in[13];
    const float* Alog     = (const float*)d_in[14];
    const float* Dp       = (const float*)d_in[15];
    const float* out_w    = (const float*)d_in[16];
    const float* mix_w    = (const float*)d_in[17];
    const float* ln_out_w = (const float*)d_in[18];
    const float* ln_out_b = (const float*)d_in[19];
    float* out = (float*)d_out;

    char* base = (char*)d_ws;
    bf16*  si     = (bf16*)(base + WS_SI);
    bf16*  u0     = (bf16*)(base + WS_U0);
    bf16*  u1     = (bf16*)(base + WS_U1);
    bf16*  xz     = (bf16*)(base + WS_XZ);
    bf16*  H      = (bf16*)(base + WS_H);
    float* Pb     = (float*)(base + WS_P);
    float* Qb     = (float*)(base + WS_Q);
    float* sinb   = (float*)(base + WS_SINB);
    bf16*  xbc    = (bf16*)(base + WS_XBC);
    bf16*  delta  = (bf16*)(base + WS_DELTA);
    bf16*  xb16   = (bf16*)(base + WS_DELTA);   // early alias (disjoint lifetime)
    float* btct   = (float*)(base + WS_BTCT);
    bf16*  mixed  = (bf16*)(base + WS_MIXED);
    bf16*  in_wb  = (bf16*)(base + WS_INWB);
    bf16*  mix_wb = (bf16*)(base + WS_MIXWB);
    bf16*  pw2b   = (bf16*)(base + WS_PW2B);
    bf16*  owT    = (bf16*)(base + WS_OWT);
    bf16*  Wp     = (bf16*)(base + WS_WP);
    bf16*  Wd     = (bf16*)(base + WS_WD);
    bf16*  xpwb   = (bf16*)(base + WS_XPWB);
    float* a2     = (float*)(base + WS_A2);
    float* wxT    = (float*)(base + WS_WXT);
    float* wzT    = (float*)(base + WS_WZT);
    float* mrs    = (float*)(base + WS_MRS);
    float* lnbp   = (float*)(base + WS_LNBP);

    // 0. merged prep: x stats + xb16, H, owT, mix_wb, in_wb, Wd, pw2b, xpwb, a2, wT, lnbp
    k_prep<<<16248, 256, 0, stream>>>(x, mrs, xb16, ln_in_b, pos_b2, lnbp,
                                      position, pos_w1, pos_b1, H,
                                      out_w, owT, mix_w, mix_wb, in_w, in_wb,
                                      dt_w, xp_w, Wd, pos_w2, pw2b, xpwb,
                                      Alog, a2, cx_w, cz_w, wxT, wzT);
    // W'[d] = mix_w[:, d*512:] @ owT[d]^T  (merged via blockIdx.z)
    gemm_mfma<bf16, 0><<<dim3(4, 4, 2), 256, 0, stream>>>(
        mix_wb, 1536, owT, 512, Wp, 512, 512, nullptr, 512, 262144, 262144, 0,
        nullptr, nullptr, nullptr, nullptr);
    // 1+2. si = (H @ pw2b^T) + LN(x)*w+b + pb2   (fused EPI=2 epilogue, bf16 x)
    gemm_mfma<bf16, 2><<<dim3(4, MM/128), 256, 0, stream>>>(
        H, 128, pw2b, 128, si, 512, 128, nullptr, 0, 0, 0, 0,
        xb16, mrs, ln_in_w, lnbp);
    // 3. in-proj
    gemm_mfma<bf16, 0><<<dim3(8, MM/128), 256, 0, stream>>>(
        si, 512, in_wb, 512, xz, 1024, 512, nullptr, 0, 0, 0, 0,
        nullptr, nullptr, nullptr, nullptr);
    // 4. conv + SiLU (4 rows/thread)
    k_conv<<<dim3(512, 2), 256, 0, stream>>>(xz, wxT, wzT, xbc, u0, u1);
    // 5a. delta[d] = clip(softplus(xbc[d] @ Wd[d]^T + dt_b[d])), both d via blockIdx.z
    gemm_mfma<bf16, 1><<<dim3(2, MM/128, 2), 256, 0, stream>>>(
        xbc, 256, Wd, 256, delta, 256, 256, dt_b,
        (long)MM*II, 65536, (long)MM*II, 256,
        nullptr, nullptr, nullptr, nullptr);
    // 5b. btct = tanh(xbc @ xpwb^T)
    k_btct<<<dim3(MM/64, 2), 256, 0, stream>>>(xbc, xpwb, btct);
    // 6. chunked scan (CHUNK=64, 256-thread blocks, 1-deep prefetch -- r11 structure)
    k_scan1<<<dim3(NCH, 16), 256, 0, stream>>>(delta, btct, xbc, a2, Pb, Qb);
    k_scan2<<<dim3(64, 2), 256, 0, stream>>>(Pb, Qb, sinb);
    k_scan3<<<dim3(NCH, 16), 256, 0, stream>>>(delta, btct, xbc, a2, Dp,
                                               sinb, u0, u1);
    // 7. mixed = u0@W'0^T + u1@W'1^T + si@Wm2^T  (bf16 out)
    gemm_mix3<<<dim3(4, MM/128), 256, 0, stream>>>(u0, u1, si,
                                                   Wp, Wp + 262144, mix_wb + 1024, 1536,
                                                   mixed);
    // 8. out = LN(mixed)  (wave-per-row, 4 rows/block)
    k_ln_out<<<MM/4, 256, 0, stream>>>(mixed, ln_out_w, ln_out_b, out);
}